// Round 15
// baseline (327.397 us; speedup 1.0000x reference)
//
#include <hip/hip_runtime.h>
#include <hip/hip_bf16.h>

// ---------------------------------------------------------------------------
// TwoLayerGCN. Round 15: spmm256 feature-split by block parity. Even blocks
// gather feats 0-127, odd blocks 128-255 of their nodes. With round-robin
// block->XCD dispatch, each XCD's private 4MB L2 sees a 12.8MB working set
// (was 25.6MB) -> ~2x L2 hit rate on the random gather. Edge stream read
// twice (+3.2MB, cheap after R14's 4B packing). spmm128 unsplit (WS already
// 12.8MB). R14 was neutral (319.4us); spmm256 six rounds stable at 56us.
// ---------------------------------------------------------------------------

typedef short v8s __attribute__((ext_vector_type(8)));
typedef float v4f __attribute__((ext_vector_type(4)));

__device__ inline unsigned bf16u(float f) {           // fp32 -> bf16 bits (RNE)
    unsigned u = __builtin_bit_cast(unsigned, f);
    return (u + 0x7fffu + ((u >> 16) & 1u)) >> 16;
}
__device__ inline float bflo(unsigned v) { return __builtin_bit_cast(float, v << 16); }
__device__ inline float bfhi(unsigned v) { return __builtin_bit_cast(float, v & 0xffff0000u); }

// ------------------- fused prep: x->bf16, degree hist, W^T -------------------
__global__ __launch_bounds__(256) void prep(
    const float* __restrict__ x, ushort* __restrict__ xh,
    const int* __restrict__ dst, int* __restrict__ deg,
    const float* __restrict__ W1, ushort* __restrict__ Wt1,
    const float* __restrict__ W2, ushort* __restrict__ Wt2, int E)
{
    int b = blockIdx.x;
    int t = threadIdx.x;
    if (b < 6250) {
        int i = b * 256 + t;                 // n4 = 1600000
        if (i < 1600000) {
            float4 v = ((const float4*)x)[i];
            unsigned lo = (bf16u(v.y) << 16) | bf16u(v.x);
            unsigned hi = (bf16u(v.w) << 16) | bf16u(v.z);
            ((uint2*)xh)[i] = make_uint2(lo, hi);
        }
    } else if (b < 9375) {
        int e = (b - 6250) * 256 + t;
        if (e < E) atomicAdd(&deg[dst[e]], 1);
    } else if (b < 9631) {
        int n = b - 9375;
        if (t < 128) Wt1[n * 128 + t] = (ushort)bf16u(W1[t * 256 + n]);
    } else {
        int n = b - 9631;
        Wt2[n * 256 + t] = (ushort)bf16u(W2[t * 256 + n]);
    }
}

// -------------- fused scan: local scan + decoupled lookback -----------------
__global__ __launch_bounds__(256) void scan_fused_k(
    const int* __restrict__ deg, int* __restrict__ off,
    int* __restrict__ cursor, int* __restrict__ bsum, int n, int E)
{
    __shared__ int s[256];
    __shared__ int psum[4];
    __shared__ int sboff;
    int tid = threadIdx.x;
    int b = blockIdx.x;
    int gid = b * 256 + tid;
    int v = (gid < n) ? deg[gid] : 0;
    s[tid] = v;
    __syncthreads();
    for (int o = 1; o < 256; o <<= 1) {
        int t = (tid >= o) ? s[tid - o] : 0;
        __syncthreads();
        s[tid] += t;
        __syncthreads();
    }
    int excl = s[tid] - v;
    int total = s[255];

    if (tid == 0) atomicExch(&bsum[b], total + 1);   // publish (sentinel +1)

    int pred = 0;
    if (tid < b) {
        int val;
        do { val = atomicAdd(&bsum[tid], 0); } while (val == 0);
        pred = val - 1;
    }
    #pragma unroll
    for (int o2 = 32; o2 > 0; o2 >>= 1) pred += __shfl_down(pred, o2, 64);
    if ((tid & 63) == 0) psum[tid >> 6] = pred;
    __syncthreads();
    if (tid == 0) sboff = psum[0] + psum[1] + psum[2] + psum[3];
    __syncthreads();

    if (gid < n) {
        int w = excl + sboff;
        off[gid] = w;
        cursor[gid] = w;
    }
    if (gid == 0) off[n] = E;
}

// packed edge: low 16 = src (N < 2^16), high 16 = bf16(weight).
// also zeroes g[128*256] (needed before gemm_pool's atomics, much later)
__global__ __launch_bounds__(256) void csr_fill(
    const int* __restrict__ src, const int* __restrict__ dst,
    const float* __restrict__ w, int* __restrict__ cursor,
    unsigned* __restrict__ edges, float* __restrict__ g, int E)
{
    int b = blockIdx.x, t = threadIdx.x;
    if (b < 128) g[b * 256 + t] = 0.f;
    int e = b * 256 + t;
    if (e >= E) return;
    int d = dst[e];
    int p = atomicAdd(&cursor[d], 1);
    edges[p] = (unsigned)src[e] | (bf16u(w[e]) << 16);
}

// ----------------------- gather SpMM (bf16 in/out) --------------------------
__global__ __launch_bounds__(256) void spmm128(
    const ushort* __restrict__ xh, const int* __restrict__ off,
    const unsigned* __restrict__ edges, ushort* __restrict__ S, int n)
{
    int node = blockIdx.x * 4 + (threadIdx.x >> 6);
    if (node >= n) return;
    int lane = threadIdx.x & 63;
    const unsigned* base = (const unsigned*)xh;   // row stride 64 uints
    int e0 = off[node], e1 = off[node + 1];
    float a0 = 0.f, a1 = 0.f;
    int e = e0;
    for (; e + 4 <= e1; e += 4) {
        unsigned ed0 = edges[e],     ed1 = edges[e + 1];
        unsigned ed2 = edges[e + 2], ed3 = edges[e + 3];
        float w0 = bfhi(ed0), w1 = bfhi(ed1);
        float w2 = bfhi(ed2), w3 = bfhi(ed3);
        unsigned v0 = base[(size_t)(ed0 & 0xffffu) * 64 + lane];
        unsigned v1 = base[(size_t)(ed1 & 0xffffu) * 64 + lane];
        unsigned v2 = base[(size_t)(ed2 & 0xffffu) * 64 + lane];
        unsigned v3 = base[(size_t)(ed3 & 0xffffu) * 64 + lane];
        a0 += bflo(v0) * w0 + bflo(v1) * w1 + bflo(v2) * w2 + bflo(v3) * w3;
        a1 += bfhi(v0) * w0 + bfhi(v1) * w1 + bfhi(v2) * w2 + bfhi(v3) * w3;
    }
    for (; e < e1; e++) {
        unsigned ed = edges[e];
        float w0 = bfhi(ed);
        unsigned v0 = base[(size_t)(ed & 0xffffu) * 64 + lane];
        a0 += bflo(v0) * w0;
        a1 += bfhi(v0) * w0;
    }
    ((unsigned*)S)[(size_t)node * 64 + lane] = (bf16u(a1) << 16) | bf16u(a0);
}

// spmm256 feature-split: even blocks do feats 0-127, odd blocks 128-255.
// Lane owns 2 feats (one uint). Grid = 2 * ceil(n/4) blocks.
__global__ __launch_bounds__(256) void spmm256h(
    const ushort* __restrict__ hh, const int* __restrict__ off,
    const unsigned* __restrict__ edges, ushort* __restrict__ S, int n)
{
    int b = blockIdx.x;
    int half = b & 1;
    int node = (b >> 1) * 4 + (threadIdx.x >> 6);
    if (node >= n) return;
    int lane = threadIdx.x & 63;
    // row stride 128 uints; this half's 64-uint window
    const unsigned* base = (const unsigned*)hh + half * 64 + lane;
    int e0 = off[node], e1 = off[node + 1];
    float a0 = 0.f, a1 = 0.f;
    int e = e0;
    for (; e + 4 <= e1; e += 4) {
        unsigned ed0 = edges[e],     ed1 = edges[e + 1];
        unsigned ed2 = edges[e + 2], ed3 = edges[e + 3];
        float w0 = bfhi(ed0), w1 = bfhi(ed1);
        float w2 = bfhi(ed2), w3 = bfhi(ed3);
        unsigned v0 = base[(size_t)(ed0 & 0xffffu) * 128];
        unsigned v1 = base[(size_t)(ed1 & 0xffffu) * 128];
        unsigned v2 = base[(size_t)(ed2 & 0xffffu) * 128];
        unsigned v3 = base[(size_t)(ed3 & 0xffffu) * 128];
        a0 += bflo(v0) * w0 + bflo(v1) * w1 + bflo(v2) * w2 + bflo(v3) * w3;
        a1 += bfhi(v0) * w0 + bfhi(v1) * w1 + bfhi(v2) * w2 + bfhi(v3) * w3;
    }
    for (; e < e1; e++) {
        unsigned ed = edges[e];
        float w0 = bfhi(ed);
        unsigned v0 = base[(size_t)(ed & 0xffffu) * 128];
        a0 += bflo(v0) * w0;
        a1 += bfhi(v0) * w0;
    }
    ((unsigned*)S)[(size_t)node * 128 + half * 64 + lane] =
        (bf16u(a1) << 16) | bf16u(a0);
}

// ----------------- LDS-tiled MFMA bf16 GEMM, 128x256 tile -------------------
// 512 threads = 8 waves (2 row-halves x 4 col-quarters), BK=32.
// POOL=false: store relu(A@W+b). POOL=true: segment-pool into g via atomics.
template <int K, bool BF16OUT, bool POOL>
__global__ __launch_bounds__(512) void gemm_tile(
    const ushort* __restrict__ A, const ushort* __restrict__ Wt,
    const float* __restrict__ bias, void* __restrict__ out,
    const int* __restrict__ seg, float* __restrict__ g, int M)
{
    __shared__ __align__(16) ushort As[128 * 32];   // 8 KB
    __shared__ __align__(16) ushort Bs[256 * 32];   // 16 KB
    __shared__ int segsh[128];

    const int tid = threadIdx.x;
    const int bm = blockIdx.x * 128;
    const int wave = tid >> 6, lane = tid & 63;
    const int wm = wave >> 2, wn = wave & 3;
    const int r = lane & 15, q = lane >> 4;

    if (POOL && tid < 128) {
        int gr = bm + tid;
        segsh[tid] = (gr < M) ? seg[gr] : 0x7fffffff;   // sentinel
    }

    const int o0 = tid * 16;           // 0..8191
    const int row0 = o0 >> 6;          // 0..127
    const int kb0 = o0 & 63;

    const char* Ab = (const char*)A;
    const char* Bb = (const char*)Wt;

    uint4 ra0, rb0, rb1;
    ra0 = *(const uint4*)(Ab + ((size_t)(bm + row0) * K) * 2 + kb0);
    rb0 = *(const uint4*)(Bb + ((size_t)(row0)       * K) * 2 + kb0);
    rb1 = *(const uint4*)(Bb + ((size_t)(row0 + 128) * K) * 2 + kb0);

    v4f acc[4][4];
    #pragma unroll
    for (int i = 0; i < 4; i++)
        #pragma unroll
        for (int j = 0; j < 4; j++) acc[i][j] = (v4f){0.f, 0.f, 0.f, 0.f};

    const int NK = K / 32;
    for (int ks = 0; ks < NK; ks++) {
        __syncthreads();
        *(uint4*)((char*)As + o0)        = ra0;
        *(uint4*)((char*)Bs + o0)        = rb0;
        *(uint4*)((char*)Bs + o0 + 8192) = rb1;
        if (ks + 1 < NK) {
            const int kof = (ks + 1) * 64;
            ra0 = *(const uint4*)(Ab + ((size_t)(bm + row0) * K) * 2 + kof + kb0);
            rb0 = *(const uint4*)(Bb + ((size_t)(row0)       * K) * 2 + kof + kb0);
            rb1 = *(const uint4*)(Bb + ((size_t)(row0 + 128) * K) * 2 + kof + kb0);
        }
        __syncthreads();

        v8s af[4], bf[4];
        #pragma unroll
        for (int i = 0; i < 4; i++)
            af[i] = *(const v8s*)(As + (wm * 64 + i * 16 + r) * 32 + q * 8);
        #pragma unroll
        for (int j = 0; j < 4; j++)
            bf[j] = *(const v8s*)(Bs + (wn * 64 + j * 16 + r) * 32 + q * 8);
        #pragma unroll
        for (int i = 0; i < 4; i++)
            #pragma unroll
            for (int j = 0; j < 4; j++)
                acc[i][j] = __builtin_amdgcn_mfma_f32_16x16x32_bf16(
                    af[i], bf[j], acc[i][j], 0, 0, 0);
    }

    if constexpr (POOL) {
        #pragma unroll
        for (int j = 0; j < 4; j++) {
            float b = bias[wn * 64 + j * 16 + r];
            #pragma unroll
            for (int i = 0; i < 4; i++)
                #pragma unroll
                for (int ii = 0; ii < 4; ii++)
                    acc[i][j][ii] = fmaxf(acc[i][j][ii] + b, 0.f);
        }
        int myseg[16];
        #pragma unroll
        for (int i = 0; i < 4; i++)
            #pragma unroll
            for (int ii = 0; ii < 4; ii++)
                myseg[i * 4 + ii] = segsh[wm * 64 + i * 16 + q * 4 + ii];
        int s_lo = segsh[0];
        int s_hi = segsh[min(127, M - 1 - bm)];
        for (int s = s_lo; s <= s_hi; s++) {
            #pragma unroll
            for (int j = 0; j < 4; j++) {
                float p = 0.f;
                #pragma unroll
                for (int i = 0; i < 4; i++)
                    #pragma unroll
                    for (int ii = 0; ii < 4; ii++)
                        if (myseg[i * 4 + ii] == s) p += acc[i][j][ii];
                p += __shfl_xor(p, 16, 64);
                p += __shfl_xor(p, 32, 64);
                if (lane < 16)
                    atomicAdd(&g[s * 256 + wn * 64 + j * 16 + r], p);
            }
        }
    } else {
        #pragma unroll
        for (int j = 0; j < 4; j++) {
            int col = wn * 64 + j * 16 + r;
            float b = bias[col];
            #pragma unroll
            for (int i = 0; i < 4; i++) {
                #pragma unroll
                for (int ii = 0; ii < 4; ii++) {
                    int row = bm + wm * 64 + i * 16 + q * 4 + ii;
                    if (row < M) {
                        float v = fmaxf(acc[i][j][ii] + b, 0.f);
                        if constexpr (BF16OUT)
                            ((ushort*)out)[(size_t)row * 256 + col] = (ushort)bf16u(v);
                        else
                            ((float*)out)[(size_t)row * 256 + col] = v;
                    }
                }
            }
        }
    }
}

// ---------------------------------- head ------------------------------------
__global__ __launch_bounds__(256) void head(
    const float* __restrict__ g, const float* __restrict__ Wd,
    const float* __restrict__ bd, const float* __restrict__ Wo,
    const float* __restrict__ bo, float* __restrict__ out)
{
    __shared__ float gr[256];
    int j = threadIdx.x;
    int gi = blockIdx.x;
    gr[j] = g[(size_t)gi * 256 + j];
    __syncthreads();
    float a2 = bd[j];
    for (int k = 0; k < 256; k++)
        a2 += gr[k] * Wd[(size_t)k * 256 + j];
    a2 = fmaxf(a2, 0.f);

    float v = a2 * Wo[j];
    #pragma unroll
    for (int off = 32; off > 0; off >>= 1)
        v += __shfl_down(v, off, 64);
    __shared__ float partial[4];
    if ((j & 63) == 0) partial[j >> 6] = v;
    __syncthreads();
    if (j == 0)
        out[gi] = partial[0] + partial[1] + partial[2] + partial[3] + bo[0];
}

extern "C" void kernel_launch(void* const* d_in, const int* in_sizes, int n_in,
                              void* d_out, int out_size, void* d_ws, size_t ws_size,
                              hipStream_t stream) {
    const float* x   = (const float*)d_in[0];
    const int*   esrc= (const int*)  d_in[1];
    const int*   edst= (const int*)  d_in[2];
    const float* ew  = (const float*)d_in[3];
    const int*   seg = (const int*)  d_in[4];
    const float* W1  = (const float*)d_in[5];
    const float* b1  = (const float*)d_in[6];
    const float* W2  = (const float*)d_in[7];
    const float* b2  = (const float*)d_in[8];
    const float* Wd  = (const float*)d_in[9];
    const float* bd  = (const float*)d_in[10];
    const float* Wo  = (const float*)d_in[11];
    const float* bo  = (const float*)d_in[12];
    float* out = (float*)d_out;

    const int N = 50000, E = 800000, G = 128, H = 256, F = 128;
    const int NPAD = 50048;            // 391 * 128
    const int NB = (N + 255) / 256;    // 196

    // workspace; region0 reused: {xh, S1}; deg+bsum contiguous (one memset)
    char* p = (char*)d_ws;
    char* region0 = p;                  p += (size_t)N * H * sizeof(float);    // 51.2 MB
    ushort* xh = (ushort*)region0;                                             // [N,128] bf16
    ushort* S1 = (ushort*)(region0 + (size_t)N * F * sizeof(ushort));          // [NPAD,128] bf16
    ushort* h1 = (ushort*)p;            p += (size_t)N * H * sizeof(ushort);   // [N,256] bf16
    ushort* S2 = (ushort*)p;            p += (size_t)NPAD * H * sizeof(ushort);// [NPAD,256] bf16
    float* g   = (float*)p;             p += (size_t)G * H * sizeof(float);
    int*   deg = (int*)p;               p += (size_t)N * sizeof(int);
    int*   bsum= (int*)p;               p += 256 * sizeof(int);                // adjacent to deg
    int*   off = (int*)p;               p += (size_t)(N + 1) * sizeof(int) + 12;
    int*   cur = (int*)p;               p += (size_t)N * sizeof(int);
    unsigned* edges=(unsigned*)p;       p += (size_t)E * sizeof(unsigned);     // packed 4B (src,w)
    ushort* Wt1= (ushort*)p;            p += (size_t)H * F * sizeof(ushort);   // [256,128]
    ushort* Wt2= (ushort*)p;            p += (size_t)H * H * sizeof(ushort);   // [256,256]

    // ---- prep (x->bf16, deg hist, W^T) + CSR build ----
    hipMemsetAsync(deg, 0, ((size_t)N + 256) * sizeof(int), stream);  // deg + bsum
    prep<<<9887, 256, 0, stream>>>(x, xh, edst, deg, W1, Wt1, W2, Wt2, E);
    scan_fused_k<<<NB, 256, 0, stream>>>(deg, off, cur, bsum, N, E);
    csr_fill<<<(E + 255) / 256, 256, 0, stream>>>(esrc, edst, ew, cur, edges, g, E);

    // ---- layer 1: S1 = A@x ; h1 = relu(S1@W1 + b1) ----
    spmm128<<<(N + 3) / 4, 256, 0, stream>>>(xh, off, edges, S1, N);
    gemm_tile<128, true, false><<<NPAD / 128, 512, 0, stream>>>(
        S1, Wt1, b1, h1, nullptr, nullptr, N);

    // ---- layer 2: S2 = A@h1 (feature-split) ; pool fused into gemm2 ----
    spmm256h<<<((N + 3) / 4) * 2, 256, 0, stream>>>(h1, off, edges, S2, N);
    gemm_tile<256, false, true><<<NPAD / 128, 512, 0, stream>>>(
        S2, Wt2, b2, nullptr, seg, g, N);

    // ---- head ----
    head<<<G, 256, 0, stream>>>(g, Wd, bd, Wo, bo, out);
}

// Round 16
// 318.381 us; speedup vs baseline: 1.0283x; 1.0283x over previous
//
#include <hip/hip_runtime.h>
#include <hip/hip_bf16.h>

// ---------------------------------------------------------------------------
// TwoLayerGCN. Round 16: REVERT R15's feature-split spmm (68us vs 56us -
// 256B random lines double issue cost; VALUBusy 32->42%, BW 3.6->2.6 TB/s
// despite -15% FETCH). Back to R14 exactly (319.0us, best verified).
// spmm256 bracketed three ways (R7 deeper MLP: worse; R15 smaller WS:
// worse; R14 smaller descriptors: neutral) -> 56us @45% peak is its
// structural optimum for random 512B gathers on this part.
// ---------------------------------------------------------------------------

typedef short v8s __attribute__((ext_vector_type(8)));
typedef float v4f __attribute__((ext_vector_type(4)));

__device__ inline unsigned bf16u(float f) {           // fp32 -> bf16 bits (RNE)
    unsigned u = __builtin_bit_cast(unsigned, f);
    return (u + 0x7fffu + ((u >> 16) & 1u)) >> 16;
}
__device__ inline float bflo(unsigned v) { return __builtin_bit_cast(float, v << 16); }
__device__ inline float bfhi(unsigned v) { return __builtin_bit_cast(float, v & 0xffff0000u); }

// ------------------- fused prep: x->bf16, degree hist, W^T -------------------
__global__ __launch_bounds__(256) void prep(
    const float* __restrict__ x, ushort* __restrict__ xh,
    const int* __restrict__ dst, int* __restrict__ deg,
    const float* __restrict__ W1, ushort* __restrict__ Wt1,
    const float* __restrict__ W2, ushort* __restrict__ Wt2, int E)
{
    int b = blockIdx.x;
    int t = threadIdx.x;
    if (b < 6250) {
        int i = b * 256 + t;                 // n4 = 1600000
        if (i < 1600000) {
            float4 v = ((const float4*)x)[i];
            unsigned lo = (bf16u(v.y) << 16) | bf16u(v.x);
            unsigned hi = (bf16u(v.w) << 16) | bf16u(v.z);
            ((uint2*)xh)[i] = make_uint2(lo, hi);
        }
    } else if (b < 9375) {
        int e = (b - 6250) * 256 + t;
        if (e < E) atomicAdd(&deg[dst[e]], 1);
    } else if (b < 9631) {
        int n = b - 9375;
        if (t < 128) Wt1[n * 128 + t] = (ushort)bf16u(W1[t * 256 + n]);
    } else {
        int n = b - 9631;
        Wt2[n * 256 + t] = (ushort)bf16u(W2[t * 256 + n]);
    }
}

// -------------- fused scan: local scan + decoupled lookback -----------------
__global__ __launch_bounds__(256) void scan_fused_k(
    const int* __restrict__ deg, int* __restrict__ off,
    int* __restrict__ cursor, int* __restrict__ bsum, int n, int E)
{
    __shared__ int s[256];
    __shared__ int psum[4];
    __shared__ int sboff;
    int tid = threadIdx.x;
    int b = blockIdx.x;
    int gid = b * 256 + tid;
    int v = (gid < n) ? deg[gid] : 0;
    s[tid] = v;
    __syncthreads();
    for (int o = 1; o < 256; o <<= 1) {
        int t = (tid >= o) ? s[tid - o] : 0;
        __syncthreads();
        s[tid] += t;
        __syncthreads();
    }
    int excl = s[tid] - v;
    int total = s[255];

    if (tid == 0) atomicExch(&bsum[b], total + 1);   // publish (sentinel +1)

    int pred = 0;
    if (tid < b) {
        int val;
        do { val = atomicAdd(&bsum[tid], 0); } while (val == 0);
        pred = val - 1;
    }
    #pragma unroll
    for (int o2 = 32; o2 > 0; o2 >>= 1) pred += __shfl_down(pred, o2, 64);
    if ((tid & 63) == 0) psum[tid >> 6] = pred;
    __syncthreads();
    if (tid == 0) sboff = psum[0] + psum[1] + psum[2] + psum[3];
    __syncthreads();

    if (gid < n) {
        int w = excl + sboff;
        off[gid] = w;
        cursor[gid] = w;
    }
    if (gid == 0) off[n] = E;
}

// packed edge: low 16 = src (N < 2^16), high 16 = bf16(weight).
// also zeroes g[128*256] (needed before gemm_pool's atomics, much later)
__global__ __launch_bounds__(256) void csr_fill(
    const int* __restrict__ src, const int* __restrict__ dst,
    const float* __restrict__ w, int* __restrict__ cursor,
    unsigned* __restrict__ edges, float* __restrict__ g, int E)
{
    int b = blockIdx.x, t = threadIdx.x;
    if (b < 128) g[b * 256 + t] = 0.f;
    int e = b * 256 + t;
    if (e >= E) return;
    int d = dst[e];
    int p = atomicAdd(&cursor[d], 1);
    edges[p] = (unsigned)src[e] | (bf16u(w[e]) << 16);
}

// ----------------------- gather SpMM (bf16 in/out) --------------------------
__global__ __launch_bounds__(256) void spmm128(
    const ushort* __restrict__ xh, const int* __restrict__ off,
    const unsigned* __restrict__ edges, ushort* __restrict__ S, int n)
{
    int node = blockIdx.x * 4 + (threadIdx.x >> 6);
    if (node >= n) return;
    int lane = threadIdx.x & 63;
    const unsigned* base = (const unsigned*)xh;   // row stride 64 uints
    int e0 = off[node], e1 = off[node + 1];
    float a0 = 0.f, a1 = 0.f;
    int e = e0;
    for (; e + 4 <= e1; e += 4) {
        unsigned ed0 = edges[e],     ed1 = edges[e + 1];
        unsigned ed2 = edges[e + 2], ed3 = edges[e + 3];
        float w0 = bfhi(ed0), w1 = bfhi(ed1);
        float w2 = bfhi(ed2), w3 = bfhi(ed3);
        unsigned v0 = base[(size_t)(ed0 & 0xffffu) * 64 + lane];
        unsigned v1 = base[(size_t)(ed1 & 0xffffu) * 64 + lane];
        unsigned v2 = base[(size_t)(ed2 & 0xffffu) * 64 + lane];
        unsigned v3 = base[(size_t)(ed3 & 0xffffu) * 64 + lane];
        a0 += bflo(v0) * w0 + bflo(v1) * w1 + bflo(v2) * w2 + bflo(v3) * w3;
        a1 += bfhi(v0) * w0 + bfhi(v1) * w1 + bfhi(v2) * w2 + bfhi(v3) * w3;
    }
    for (; e < e1; e++) {
        unsigned ed = edges[e];
        float w0 = bfhi(ed);
        unsigned v0 = base[(size_t)(ed & 0xffffu) * 64 + lane];
        a0 += bflo(v0) * w0;
        a1 += bfhi(v0) * w0;
    }
    ((unsigned*)S)[(size_t)node * 64 + lane] = (bf16u(a1) << 16) | bf16u(a0);
}

__global__ __launch_bounds__(256) void spmm256(
    const ushort* __restrict__ hh, const int* __restrict__ off,
    const unsigned* __restrict__ edges, ushort* __restrict__ S, int n)
{
    int node = blockIdx.x * 4 + (threadIdx.x >> 6);
    if (node >= n) return;
    int lane = threadIdx.x & 63;
    const uint2* base = (const uint2*)hh;          // row stride 64 uint2
    int e0 = off[node], e1 = off[node + 1];
    float a0 = 0.f, a1 = 0.f, a2 = 0.f, a3 = 0.f;
    int e = e0;
    for (; e + 4 <= e1; e += 4) {
        unsigned ed0 = edges[e],     ed1 = edges[e + 1];
        unsigned ed2 = edges[e + 2], ed3 = edges[e + 3];
        float w0 = bfhi(ed0), w1 = bfhi(ed1);
        float w2 = bfhi(ed2), w3 = bfhi(ed3);
        uint2 v0 = base[(size_t)(ed0 & 0xffffu) * 64 + lane];
        uint2 v1 = base[(size_t)(ed1 & 0xffffu) * 64 + lane];
        uint2 v2 = base[(size_t)(ed2 & 0xffffu) * 64 + lane];
        uint2 v3 = base[(size_t)(ed3 & 0xffffu) * 64 + lane];
        a0 += bflo(v0.x) * w0 + bflo(v1.x) * w1 + bflo(v2.x) * w2 + bflo(v3.x) * w3;
        a1 += bfhi(v0.x) * w0 + bfhi(v1.x) * w1 + bfhi(v2.x) * w2 + bfhi(v3.x) * w3;
        a2 += bflo(v0.y) * w0 + bflo(v1.y) * w1 + bflo(v2.y) * w2 + bflo(v3.y) * w3;
        a3 += bfhi(v0.y) * w0 + bfhi(v1.y) * w1 + bfhi(v2.y) * w2 + bfhi(v3.y) * w3;
    }
    for (; e < e1; e++) {
        unsigned ed = edges[e];
        float w0 = bfhi(ed);
        uint2 v0 = base[(size_t)(ed & 0xffffu) * 64 + lane];
        a0 += bflo(v0.x) * w0;
        a1 += bfhi(v0.x) * w0;
        a2 += bflo(v0.y) * w0;
        a3 += bfhi(v0.y) * w0;
    }
    uint2 o;
    o.x = (bf16u(a1) << 16) | bf16u(a0);
    o.y = (bf16u(a3) << 16) | bf16u(a2);
    ((uint2*)S)[(size_t)node * 64 + lane] = o;
}

// ----------------- LDS-tiled MFMA bf16 GEMM, 128x256 tile -------------------
// 512 threads = 8 waves (2 row-halves x 4 col-quarters), BK=32.
// POOL=false: store relu(A@W+b). POOL=true: segment-pool into g via atomics.
template <int K, bool BF16OUT, bool POOL>
__global__ __launch_bounds__(512) void gemm_tile(
    const ushort* __restrict__ A, const ushort* __restrict__ Wt,
    const float* __restrict__ bias, void* __restrict__ out,
    const int* __restrict__ seg, float* __restrict__ g, int M)
{
    __shared__ __align__(16) ushort As[128 * 32];   // 8 KB
    __shared__ __align__(16) ushort Bs[256 * 32];   // 16 KB
    __shared__ int segsh[128];

    const int tid = threadIdx.x;
    const int bm = blockIdx.x * 128;
    const int wave = tid >> 6, lane = tid & 63;
    const int wm = wave >> 2, wn = wave & 3;
    const int r = lane & 15, q = lane >> 4;

    if (POOL && tid < 128) {
        int gr = bm + tid;
        segsh[tid] = (gr < M) ? seg[gr] : 0x7fffffff;   // sentinel
    }

    const int o0 = tid * 16;           // 0..8191
    const int row0 = o0 >> 6;          // 0..127
    const int kb0 = o0 & 63;

    const char* Ab = (const char*)A;
    const char* Bb = (const char*)Wt;

    uint4 ra0, rb0, rb1;
    ra0 = *(const uint4*)(Ab + ((size_t)(bm + row0) * K) * 2 + kb0);
    rb0 = *(const uint4*)(Bb + ((size_t)(row0)       * K) * 2 + kb0);
    rb1 = *(const uint4*)(Bb + ((size_t)(row0 + 128) * K) * 2 + kb0);

    v4f acc[4][4];
    #pragma unroll
    for (int i = 0; i < 4; i++)
        #pragma unroll
        for (int j = 0; j < 4; j++) acc[i][j] = (v4f){0.f, 0.f, 0.f, 0.f};

    const int NK = K / 32;
    for (int ks = 0; ks < NK; ks++) {
        __syncthreads();
        *(uint4*)((char*)As + o0)        = ra0;
        *(uint4*)((char*)Bs + o0)        = rb0;
        *(uint4*)((char*)Bs + o0 + 8192) = rb1;
        if (ks + 1 < NK) {
            const int kof = (ks + 1) * 64;
            ra0 = *(const uint4*)(Ab + ((size_t)(bm + row0) * K) * 2 + kof + kb0);
            rb0 = *(const uint4*)(Bb + ((size_t)(row0)       * K) * 2 + kof + kb0);
            rb1 = *(const uint4*)(Bb + ((size_t)(row0 + 128) * K) * 2 + kof + kb0);
        }
        __syncthreads();

        v8s af[4], bf[4];
        #pragma unroll
        for (int i = 0; i < 4; i++)
            af[i] = *(const v8s*)(As + (wm * 64 + i * 16 + r) * 32 + q * 8);
        #pragma unroll
        for (int j = 0; j < 4; j++)
            bf[j] = *(const v8s*)(Bs + (wn * 64 + j * 16 + r) * 32 + q * 8);
        #pragma unroll
        for (int i = 0; i < 4; i++)
            #pragma unroll
            for (int j = 0; j < 4; j++)
                acc[i][j] = __builtin_amdgcn_mfma_f32_16x16x32_bf16(
                    af[i], bf[j], acc[i][j], 0, 0, 0);
    }

    if constexpr (POOL) {
        #pragma unroll
        for (int j = 0; j < 4; j++) {
            float b = bias[wn * 64 + j * 16 + r];
            #pragma unroll
            for (int i = 0; i < 4; i++)
                #pragma unroll
                for (int ii = 0; ii < 4; ii++)
                    acc[i][j][ii] = fmaxf(acc[i][j][ii] + b, 0.f);
        }
        int myseg[16];
        #pragma unroll
        for (int i = 0; i < 4; i++)
            #pragma unroll
            for (int ii = 0; ii < 4; ii++)
                myseg[i * 4 + ii] = segsh[wm * 64 + i * 16 + q * 4 + ii];
        int s_lo = segsh[0];
        int s_hi = segsh[min(127, M - 1 - bm)];
        for (int s = s_lo; s <= s_hi; s++) {
            #pragma unroll
            for (int j = 0; j < 4; j++) {
                float p = 0.f;
                #pragma unroll
                for (int i = 0; i < 4; i++)
                    #pragma unroll
                    for (int ii = 0; ii < 4; ii++)
                        if (myseg[i * 4 + ii] == s) p += acc[i][j][ii];
                p += __shfl_xor(p, 16, 64);
                p += __shfl_xor(p, 32, 64);
                if (lane < 16)
                    atomicAdd(&g[s * 256 + wn * 64 + j * 16 + r], p);
            }
        }
    } else {
        #pragma unroll
        for (int j = 0; j < 4; j++) {
            int col = wn * 64 + j * 16 + r;
            float b = bias[col];
            #pragma unroll
            for (int i = 0; i < 4; i++) {
                #pragma unroll
                for (int ii = 0; ii < 4; ii++) {
                    int row = bm + wm * 64 + i * 16 + q * 4 + ii;
                    if (row < M) {
                        float v = fmaxf(acc[i][j][ii] + b, 0.f);
                        if constexpr (BF16OUT)
                            ((ushort*)out)[(size_t)row * 256 + col] = (ushort)bf16u(v);
                        else
                            ((float*)out)[(size_t)row * 256 + col] = v;
                    }
                }
            }
        }
    }
}

// ---------------------------------- head ------------------------------------
__global__ __launch_bounds__(256) void head(
    const float* __restrict__ g, const float* __restrict__ Wd,
    const float* __restrict__ bd, const float* __restrict__ Wo,
    const float* __restrict__ bo, float* __restrict__ out)
{
    __shared__ float gr[256];
    int j = threadIdx.x;
    int gi = blockIdx.x;
    gr[j] = g[(size_t)gi * 256 + j];
    __syncthreads();
    float a2 = bd[j];
    for (int k = 0; k < 256; k++)
        a2 += gr[k] * Wd[(size_t)k * 256 + j];
    a2 = fmaxf(a2, 0.f);

    float v = a2 * Wo[j];
    #pragma unroll
    for (int off = 32; off > 0; off >>= 1)
        v += __shfl_down(v, off, 64);
    __shared__ float partial[4];
    if ((j & 63) == 0) partial[j >> 6] = v;
    __syncthreads();
    if (j == 0)
        out[gi] = partial[0] + partial[1] + partial[2] + partial[3] + bo[0];
}

extern "C" void kernel_launch(void* const* d_in, const int* in_sizes, int n_in,
                              void* d_out, int out_size, void* d_ws, size_t ws_size,
                              hipStream_t stream) {
    const float* x   = (const float*)d_in[0];
    const int*   esrc= (const int*)  d_in[1];
    const int*   edst= (const int*)  d_in[2];
    const float* ew  = (const float*)d_in[3];
    const int*   seg = (const int*)  d_in[4];
    const float* W1  = (const float*)d_in[5];
    const float* b1  = (const float*)d_in[6];
    const float* W2  = (const float*)d_in[7];
    const float* b2  = (const float*)d_in[8];
    const float* Wd  = (const float*)d_in[9];
    const float* bd  = (const float*)d_in[10];
    const float* Wo  = (const float*)d_in[11];
    const float* bo  = (const float*)d_in[12];
    float* out = (float*)d_out;

    const int N = 50000, E = 800000, G = 128, H = 256, F = 128;
    const int NPAD = 50048;            // 391 * 128
    const int NB = (N + 255) / 256;    // 196

    // workspace; region0 reused: {xh, S1}; deg+bsum contiguous (one memset)
    char* p = (char*)d_ws;
    char* region0 = p;                  p += (size_t)N * H * sizeof(float);    // 51.2 MB
    ushort* xh = (ushort*)region0;                                             // [N,128] bf16
    ushort* S1 = (ushort*)(region0 + (size_t)N * F * sizeof(ushort));          // [NPAD,128] bf16
    ushort* h1 = (ushort*)p;            p += (size_t)N * H * sizeof(ushort);   // [N,256] bf16
    ushort* S2 = (ushort*)p;            p += (size_t)NPAD * H * sizeof(ushort);// [NPAD,256] bf16
    float* g   = (float*)p;             p += (size_t)G * H * sizeof(float);
    int*   deg = (int*)p;               p += (size_t)N * sizeof(int);
    int*   bsum= (int*)p;               p += 256 * sizeof(int);                // adjacent to deg
    int*   off = (int*)p;               p += (size_t)(N + 1) * sizeof(int) + 12;
    int*   cur = (int*)p;               p += (size_t)N * sizeof(int);
    unsigned* edges=(unsigned*)p;       p += (size_t)E * sizeof(unsigned);     // packed 4B (src,w)
    ushort* Wt1= (ushort*)p;            p += (size_t)H * F * sizeof(ushort);   // [256,128]
    ushort* Wt2= (ushort*)p;            p += (size_t)H * H * sizeof(ushort);   // [256,256]

    // ---- prep (x->bf16, deg hist, W^T) + CSR build ----
    hipMemsetAsync(deg, 0, ((size_t)N + 256) * sizeof(int), stream);  // deg + bsum
    prep<<<9887, 256, 0, stream>>>(x, xh, edst, deg, W1, Wt1, W2, Wt2, E);
    scan_fused_k<<<NB, 256, 0, stream>>>(deg, off, cur, bsum, N, E);
    csr_fill<<<(E + 255) / 256, 256, 0, stream>>>(esrc, edst, ew, cur, edges, g, E);

    // ---- layer 1: S1 = A@x ; h1 = relu(S1@W1 + b1) ----
    spmm128<<<(N + 3) / 4, 256, 0, stream>>>(xh, off, edges, S1, N);
    gemm_tile<128, true, false><<<NPAD / 128, 512, 0, stream>>>(
        S1, Wt1, b1, h1, nullptr, nullptr, N);

    // ---- layer 2: S2 = A@h1 ; pool(relu(S2@W2+b2)) fused into epilogue ----
    spmm256<<<(N + 3) / 4, 256, 0, stream>>>(h1, off, edges, S2, N);
    gemm_tile<256, false, true><<<NPAD / 128, 512, 0, stream>>>(
        S2, Wt2, b2, nullptr, seg, g, N);

    // ---- head ----
    head<<<G, 256, 0, stream>>>(g, Wd, bd, Wo, bo, out);
}